// Round 4
// baseline (299.324 us; speedup 1.0000x reference)
//
#include <hip/hip_runtime.h>
#include <math.h>

#define WE 300
#define DEp 256
#define VV 50000
#define DDim 100000
#define BB 4096
#define NGc 10
#define RVT_STRIDE 304   // padded row stride (floats) for rvT, 16B-aligned

__device__ __forceinline__ float wave_reduce(float v) {
    #pragma unroll
    for (int o = 32; o > 0; o >>= 1) v += __shfl_down(v, o, 64);
    return v;
}

// butterfly: all 64 lanes end with the total
__device__ __forceinline__ float wave_allreduce(float v) {
    #pragma unroll
    for (int o = 32; o > 0; o >>= 1) v += __shfl_xor(v, o, 64);
    return v;
}

// log(sigmoid(x)), numerically stable
__device__ __forceinline__ float logsigf(float x) {
    return (x >= 0.f) ? -log1pf(expf(-x)) : x - log1pf(expf(x));
}

__global__ void k_init(double* p, int n) {
    int i = blockIdx.x * blockDim.x + threadIdx.x;
    if (i < n) p[i] = 0.0;
}

// ---- rd transpose: 256 x 100000 -> 100000 x 256, fused sum(rd*rd). ----
// PERSISTENT + REGISTER-PIPELINED: 1024 blocks loop over 3125 tiles
// (32 cols x 256 rows). Next tile's global loads are issued BEFORE the
// current tile's store phase, so each wave keeps continuous read+write
// streams in flight (copy-like), instead of dead load->barrier->store phases.
__global__ __launch_bounds__(256) void k_trd(const float* __restrict__ in,
                                             float* __restrict__ out,
                                             double* __restrict__ reg_acc) {
    __shared__ float4 tile[32 * 64];
    __shared__ float part[4];
    const int N = DDim;
    const int NT = 3125;            // 100000 / 32, exact
    int t = threadIdx.x;
    int qn = t & 7;                 // col-quad 0..7 (32 cols per tile)
    int qmA = t >> 3;               // row-quad 0..31
    int qmB = qmA + 32;             // row-quad 32..63
    int G = gridDim.x;
    float ss = 0.f;
    float4 rA[4], rB[4];
    int cur = blockIdx.x;
    {   // prefetch first tile
        int n = cur * 32 + qn * 4;
        const float* pA = in + (size_t)(qmA * 4) * N + n;
        const float* pB = in + (size_t)(qmB * 4) * N + n;
        #pragma unroll
        for (int e = 0; e < 4; ++e) rA[e] = *(const float4*)(pA + (size_t)e * N);
        #pragma unroll
        for (int e = 0; e < 4; ++e) rB[e] = *(const float4*)(pB + (size_t)e * N);
    }
    while (true) {
        int nxt = cur + G;
        __syncthreads();            // previous store phase done reading LDS
        #pragma unroll
        for (int e = 0; e < 4; ++e) {
            ss += rA[e].x * rA[e].x + rA[e].y * rA[e].y + rA[e].z * rA[e].z + rA[e].w * rA[e].w;
            ss += rB[e].x * rB[e].x + rB[e].y * rB[e].y + rB[e].z * rB[e].z + rB[e].w * rB[e].w;
        }
        int c0 = qn * 4;
        tile[(c0 + 0) * 64 + (qmA ^ (c0 + 0))] = make_float4(rA[0].x, rA[1].x, rA[2].x, rA[3].x);
        tile[(c0 + 1) * 64 + (qmA ^ (c0 + 1))] = make_float4(rA[0].y, rA[1].y, rA[2].y, rA[3].y);
        tile[(c0 + 2) * 64 + (qmA ^ (c0 + 2))] = make_float4(rA[0].z, rA[1].z, rA[2].z, rA[3].z);
        tile[(c0 + 3) * 64 + (qmA ^ (c0 + 3))] = make_float4(rA[0].w, rA[1].w, rA[2].w, rA[3].w);
        tile[(c0 + 0) * 64 + (qmB ^ (c0 + 0))] = make_float4(rB[0].x, rB[1].x, rB[2].x, rB[3].x);
        tile[(c0 + 1) * 64 + (qmB ^ (c0 + 1))] = make_float4(rB[0].y, rB[1].y, rB[2].y, rB[3].y);
        tile[(c0 + 2) * 64 + (qmB ^ (c0 + 2))] = make_float4(rB[0].z, rB[1].z, rB[2].z, rB[3].z);
        tile[(c0 + 3) * 64 + (qmB ^ (c0 + 3))] = make_float4(rB[0].w, rB[1].w, rB[2].w, rB[3].w);
        __syncthreads();
        bool more = (nxt < NT);
        if (more) {                 // issue next tile's loads; they fly during stores
            int n = nxt * 32 + qn * 4;
            const float* pA = in + (size_t)(qmA * 4) * N + n;
            const float* pB = in + (size_t)(qmB * 4) * N + n;
            #pragma unroll
            for (int e = 0; e < 4; ++e) rA[e] = *(const float4*)(pA + (size_t)e * N);
            #pragma unroll
            for (int e = 0; e < 4; ++e) rB[e] = *(const float4*)(pB + (size_t)e * N);
        }
        size_t base = (size_t)cur * (32 * DEp);   // floats; contiguous 32KB span
        #pragma unroll
        for (int i = 0; i < 8; ++i) {
            int j = i * 256 + t;    // float4 index within block's 2048-f4 region
            int nl = j >> 6;
            int m4 = j & 63;
            *(float4*)(out + base + (size_t)j * 4) = tile[nl * 64 + (m4 ^ nl)];
        }
        if (!more) break;
        cur = nxt;
    }
    float r = wave_reduce(ss);
    int lane = t & 63, wv = t >> 6;
    if (lane == 0) part[wv] = r;
    __syncthreads();
    if (t == 0)
        atomicAdd(reg_acc, (double)(part[0] + part[1] + part[2] + part[3]));
}

// ---- rv transpose: 300 x 50000 -> 50000 x 304 (padded rows). ----
// Same persistent register-pipelined structure; 1563 tiles of 32 cols x 300 rows.
__global__ __launch_bounds__(256) void k_trv(const float* __restrict__ in,
                                             float* __restrict__ out) {
    __shared__ float4 tile[32 * 80];
    const int N = VV;
    const int NT = 1563;            // ceil(50000/32)
    int t = threadIdx.x;
    int qn = t & 7;
    int qmA = t >> 3;               // 0..31
    int qmB = qmA + 32;             // 32..63
    int qmC = qmA + 64;             // 64..95; active only if <75
    bool hasC = (t < 88);           // qmC <= 74
    int G = gridDim.x;
    float4 rA[4], rB[4], rC[4];
    int cur = blockIdx.x;
    {
        int n = cur * 32 + qn * 4;
        bool ok = (n < N);
        const float* pA = in + (size_t)(qmA * 4) * N + n;
        const float* pB = in + (size_t)(qmB * 4) * N + n;
        const float* pC = in + (size_t)(qmC * 4) * N + n;
        #pragma unroll
        for (int e = 0; e < 4; ++e) {
            rA[e] = ok ? *(const float4*)(pA + (size_t)e * N) : make_float4(0.f, 0.f, 0.f, 0.f);
            rB[e] = ok ? *(const float4*)(pB + (size_t)e * N) : make_float4(0.f, 0.f, 0.f, 0.f);
            rC[e] = (ok && hasC) ? *(const float4*)(pC + (size_t)e * N) : make_float4(0.f, 0.f, 0.f, 0.f);
        }
    }
    while (true) {
        int nxt = cur + G;
        __syncthreads();
        int c0 = qn * 4;
        tile[(c0 + 0) * 80 + (qmA ^ ((c0 + 0) & 7))] = make_float4(rA[0].x, rA[1].x, rA[2].x, rA[3].x);
        tile[(c0 + 1) * 80 + (qmA ^ ((c0 + 1) & 7))] = make_float4(rA[0].y, rA[1].y, rA[2].y, rA[3].y);
        tile[(c0 + 2) * 80 + (qmA ^ ((c0 + 2) & 7))] = make_float4(rA[0].z, rA[1].z, rA[2].z, rA[3].z);
        tile[(c0 + 3) * 80 + (qmA ^ ((c0 + 3) & 7))] = make_float4(rA[0].w, rA[1].w, rA[2].w, rA[3].w);
        tile[(c0 + 0) * 80 + (qmB ^ ((c0 + 0) & 7))] = make_float4(rB[0].x, rB[1].x, rB[2].x, rB[3].x);
        tile[(c0 + 1) * 80 + (qmB ^ ((c0 + 1) & 7))] = make_float4(rB[0].y, rB[1].y, rB[2].y, rB[3].y);
        tile[(c0 + 2) * 80 + (qmB ^ ((c0 + 2) & 7))] = make_float4(rB[0].z, rB[1].z, rB[2].z, rB[3].z);
        tile[(c0 + 3) * 80 + (qmB ^ ((c0 + 3) & 7))] = make_float4(rB[0].w, rB[1].w, rB[2].w, rB[3].w);
        if (hasC) {
            tile[(c0 + 0) * 80 + (qmC ^ ((c0 + 0) & 7))] = make_float4(rC[0].x, rC[1].x, rC[2].x, rC[3].x);
            tile[(c0 + 1) * 80 + (qmC ^ ((c0 + 1) & 7))] = make_float4(rC[0].y, rC[1].y, rC[2].y, rC[3].y);
            tile[(c0 + 2) * 80 + (qmC ^ ((c0 + 2) & 7))] = make_float4(rC[0].z, rC[1].z, rC[2].z, rC[3].z);
            tile[(c0 + 3) * 80 + (qmC ^ ((c0 + 3) & 7))] = make_float4(rC[0].w, rC[1].w, rC[2].w, rC[3].w);
        }
        __syncthreads();
        bool more = (nxt < NT);
        if (more) {
            int n = nxt * 32 + qn * 4;
            bool ok = (n < N);
            const float* pA = in + (size_t)(qmA * 4) * N + n;
            const float* pB = in + (size_t)(qmB * 4) * N + n;
            const float* pC = in + (size_t)(qmC * 4) * N + n;
            #pragma unroll
            for (int e = 0; e < 4; ++e) {
                rA[e] = ok ? *(const float4*)(pA + (size_t)e * N) : make_float4(0.f, 0.f, 0.f, 0.f);
                rB[e] = ok ? *(const float4*)(pB + (size_t)e * N) : make_float4(0.f, 0.f, 0.f, 0.f);
                rC[e] = (ok && hasC) ? *(const float4*)(pC + (size_t)e * N) : make_float4(0.f, 0.f, 0.f, 0.f);
            }
        }
        size_t base = (size_t)cur * (32 * 76);   // float4 units; contiguous span
        float4* out4 = (float4*)out;
        #pragma unroll
        for (int i = 0; i < 10; ++i) {
            int j = i * 256 + t;
            if (j < 2432) {         // 32 * 76
                int nl = j / 76;
                int m4 = j - nl * 76;   // 75 == pad column: LDS junk, never read back
                if (cur * 32 + nl < N)
                    out4[base + j] = tile[nl * 80 + (m4 ^ (nl & 7))];
            }
        }
        if (!more) break;
        cur = nxt;
    }
}

// ---- Coalesced path (uses rvT / rdT) ----

// One WAVE per b: lane l owns de = 4l..4l+3 (float4), lanes 0..10 cover the
// 256..299 tail. Butterfly reduce, no LDS, no barriers.
__global__ __launch_bounds__(256) void k_gather2(const float* __restrict__ rvT,
                                                 const int* __restrict__ wid,
                                                 float* __restrict__ normed) {
    int wv = threadIdx.x >> 6, lane = threadIdx.x & 63;
    int b = blockIdx.x * 4 + wv;
    int id = 0;
    if (lane < NGc) id = wid[b * NGc + lane];
    float4 a  = make_float4(0.f, 0.f, 0.f, 0.f);
    float4 a2 = make_float4(0.f, 0.f, 0.f, 0.f);
    #pragma unroll
    for (int ng = 0; ng < NGc; ++ng) {
        int rid = __shfl(id, ng, 64);
        const float* row = rvT + (size_t)rid * RVT_STRIDE;
        float4 v = *(const float4*)(row + lane * 4);
        a.x += v.x; a.y += v.y; a.z += v.z; a.w += v.w;
        if (lane < 11) {
            float4 w = *(const float4*)(row + 256 + lane * 4);
            a2.x += w.x; a2.y += w.y; a2.z += w.z; a2.w += w.w;
        }
    }
    a.x *= 0.1f; a.y *= 0.1f; a.z *= 0.1f; a.w *= 0.1f;
    a2.x *= 0.1f; a2.y *= 0.1f; a2.z *= 0.1f; a2.w *= 0.1f;
    float ss = a.x * a.x + a.y * a.y + a.z * a.z + a.w * a.w
             + a2.x * a2.x + a2.y * a2.y + a2.z * a2.z + a2.w * a2.w;
    float s = wave_allreduce(ss);
    float s_inv = 1.0f / sqrtf(s);
    float* orow = normed + (size_t)b * WE;
    *(float4*)(orow + lane * 4) =
        make_float4(a.x * s_inv, a.y * s_inv, a.z * s_inv, a.w * s_inv);
    if (lane < 11)
        *(float4*)(orow + 256 + lane * 4) =
            make_float4(a2.x * s_inv, a2.y * s_inv, a2.z * s_inv, a2.w * s_inv);
}

// One WAVE per b: float4 loads, 11 independent gathers in flight, butterfly
// reduces, sums distributed to lanes 0..10 -> parallel logsig, 1 atomic/block.
__global__ __launch_bounds__(256) void k_loss2(const float* __restrict__ tpre,
                                               const float* __restrict__ meanf,
                                               const float* __restrict__ scalef,
                                               const float* __restrict__ beta,
                                               const float* __restrict__ rdT,
                                               const int* __restrict__ doc_ids,
                                               const int* __restrict__ neg_ids,
                                               double* __restrict__ acc) {
    int wv = threadIdx.x >> 6, lane = threadIdx.x & 63;
    int b = blockIdx.x * 4 + wv;

    float4 t4  = *(const float4*)(tpre + (size_t)b * DEp + lane * 4);
    float4 m4  = *(const float4*)(meanf + lane * 4);
    float4 sc4 = *(const float4*)(scalef + lane * 4);
    float4 be4 = *(const float4*)(beta + lane * 4);
    float tv0 = fminf(1.f, fmaxf(-1.f, (t4.x - m4.x) * sc4.x + be4.x));
    float tv1 = fminf(1.f, fmaxf(-1.f, (t4.y - m4.y) * sc4.y + be4.y));
    float tv2 = fminf(1.f, fmaxf(-1.f, (t4.z - m4.z) * sc4.z + be4.z));
    float tv3 = fminf(1.f, fmaxf(-1.f, (t4.w - m4.w) * sc4.w + be4.w));

    int id = 0;
    if (lane == 0) id = doc_ids[b];
    else if (lane < 11) id = neg_ids[b * NGc + lane - 1];

    float xv = 0.f;
    #pragma unroll
    for (int j = 0; j < 11; ++j) {
        int rid = __shfl(id, j, 64);
        float4 r4 = *(const float4*)(rdT + (size_t)rid * DEp + lane * 4);
        float p = tv0 * r4.x + tv1 * r4.y + tv2 * r4.z + tv3 * r4.w;
        p = wave_allreduce(p);
        if (lane == j) xv = p;
    }
    float contrib = 0.f;
    if (lane == 0)      contrib = 10.f * fminf(logsigf(xv), -1.0005003e-3f);
    else if (lane < 11) contrib = fmaxf(logsigf(-xv), -4.6051702f);
    #pragma unroll
    for (int o = 8; o > 0; o >>= 1) contrib += __shfl_down(contrib, o, 16);

    __shared__ float bp[4];
    if (lane == 0) bp[wv] = contrib;
    __syncthreads();
    if (threadIdx.x == 0)
        atomicAdd(acc, (double)(0.55f * (bp[0] + bp[1] + bp[2] + bp[3])));
}

// ---- Fallback (strided) path ----

__global__ __launch_bounds__(320) void k_gather(const float* __restrict__ rv,
                                                const int* __restrict__ wid,
                                                float* __restrict__ normed) {
    int b = blockIdx.x;
    int tid = threadIdx.x;
    __shared__ int ids[NGc];
    __shared__ float wpart[5];
    __shared__ float s_inv;
    if (tid < NGc) ids[tid] = wid[b * NGc + tid];
    __syncthreads();
    float g = 0.f;
    if (tid < WE) {
        const float* row = rv + (size_t)tid * VV;
        #pragma unroll
        for (int ng = 0; ng < NGc; ++ng) g += row[ids[ng]];
        g *= 0.1f;
    }
    float r = wave_reduce(g * g);
    int lane = tid & 63, wv = tid >> 6;
    if (lane == 0) wpart[wv] = r;
    __syncthreads();
    if (tid == 0) {
        float s = wpart[0] + wpart[1] + wpart[2] + wpart[3] + wpart[4];
        s_inv = 1.0f / sqrtf(s);
    }
    __syncthreads();
    if (tid < WE) normed[(size_t)b * WE + tid] = g * s_inv;
}

__global__ __launch_bounds__(256) void k_loss(const float* __restrict__ tpre,
                                              const float* __restrict__ meanf,
                                              const float* __restrict__ scalef,
                                              const float* __restrict__ beta,
                                              const float* __restrict__ rd,
                                              const int* __restrict__ doc_ids,
                                              const int* __restrict__ neg_ids,
                                              double* __restrict__ acc) {
    int b = blockIdx.x;
    int de = threadIdx.x;
    float t = tpre[(size_t)b * DEp + de];
    float tv = (t - meanf[de]) * scalef[de] + beta[de];
    tv = fminf(1.f, fmaxf(-1.f, tv));
    const float* rdrow = rd + (size_t)de * DDim;
    __shared__ int ids[11];
    if (de == 0) ids[0] = doc_ids[b];
    if (de >= 1 && de < 11) ids[de] = neg_ids[b * NGc + de - 1];
    __syncthreads();
    float prod[11];
    #pragma unroll
    for (int j = 0; j < 11; ++j) prod[j] = tv * rdrow[ids[j]];
    __shared__ float part[11][4];
    int lane = de & 63, wv = de >> 6;
    #pragma unroll
    for (int j = 0; j < 11; ++j) {
        float r = wave_reduce(prod[j]);
        if (lane == 0) part[j][wv] = r;
    }
    __syncthreads();
    if (de == 0) {
        float x0 = part[0][0] + part[0][1] + part[0][2] + part[0][3];
        float total = 10.f * fminf(logsigf(x0), -1.0005003e-3f);
        #pragma unroll
        for (int j = 1; j < 11; ++j) {
            float xj = part[j][0] + part[j][1] + part[j][2] + part[j][3];
            total += fmaxf(logsigf(-xj), -4.6051702f);
        }
        atomicAdd(acc, (double)(0.55f * total));
    }
}

// ---- Shared middle kernels ----

__global__ __launch_bounds__(256) void k_gemm(const float* __restrict__ proj,
                                              const float* __restrict__ normed,
                                              float* __restrict__ tpre) {
    __shared__ float As[64 * 33];
    __shared__ float Bs[64 * 33];
    int tid = threadIdx.x;
    int tx = tid & 15, ty = tid >> 4;
    int de0 = blockIdx.y * 64;
    int b0  = blockIdx.x * 64;
    float acc[4][4] = {};
    int f = tid & 7, r0 = tid >> 3;
    for (int kt = 0; kt < 10; ++kt) {
        int k0 = kt * 32;
        __syncthreads();
        for (int rr = r0; rr < 64; rr += 32) {
            int k = k0 + f * 4;
            float4 va = make_float4(0.f, 0.f, 0.f, 0.f);
            float4 vb = make_float4(0.f, 0.f, 0.f, 0.f);
            if (k + 3 < WE) {
                va = *(const float4*)(proj + (size_t)(de0 + rr) * WE + k);
                vb = *(const float4*)(normed + (size_t)(b0 + rr) * WE + k);
            }
            float* ap = &As[rr * 33 + f * 4];
            ap[0] = va.x; ap[1] = va.y; ap[2] = va.z; ap[3] = va.w;
            float* bp = &Bs[rr * 33 + f * 4];
            bp[0] = vb.x; bp[1] = vb.y; bp[2] = vb.z; bp[3] = vb.w;
        }
        __syncthreads();
        #pragma unroll
        for (int k = 0; k < 32; ++k) {
            float a[4], bv[4];
            #pragma unroll
            for (int i = 0; i < 4; ++i) a[i] = As[(tx * 4 + i) * 33 + k];
            #pragma unroll
            for (int j = 0; j < 4; ++j) bv[j] = Bs[(ty * 4 + j) * 33 + k];
            #pragma unroll
            for (int j = 0; j < 4; ++j)
                #pragma unroll
                for (int i = 0; i < 4; ++i) acc[j][i] += a[i] * bv[j];
        }
    }
    #pragma unroll
    for (int jb = 0; jb < 4; ++jb) {
        int b = b0 + ty * 4 + jb;
        float4 v = make_float4(acc[jb][0], acc[jb][1], acc[jb][2], acc[jb][3]);
        *(float4*)(tpre + (size_t)b * DEp + de0 + tx * 4) = v;
    }
}

__global__ __launch_bounds__(256) void k_stats1(const float* __restrict__ tpre,
                                                double* __restrict__ rowsum,
                                                double* __restrict__ rowsq) {
    int de = threadIdx.x;
    int c0 = blockIdx.x * 64;
    float s = 0.f, ss = 0.f;
    for (int i = 0; i < 64; ++i) {
        float v = tpre[(size_t)(c0 + i) * DEp + de];
        s += v; ss += v * v;
    }
    atomicAdd(&rowsum[de], (double)s);
    atomicAdd(&rowsq[de], (double)ss);
}

__global__ void k_stats2(const double* __restrict__ rowsum, const double* __restrict__ rowsq,
                         float* __restrict__ meanf, float* __restrict__ scalef) {
    int de = threadIdx.x;
    double s = rowsum[de], ss = rowsq[de];
    double mean = s / (double)BB;
    double var = (ss - s * s / (double)BB) / (double)(BB - 1);
    double stdv = sqrt(var);
    meanf[de]  = (float)mean;
    scalef[de] = (float)(1.0 / sqrt(stdv));   // reference divides by sqrt(std) = var^0.25
}

__global__ __launch_bounds__(256) void k_reg(const float4* __restrict__ p, int n4,
                                             double* __restrict__ acc) {
    int idx = blockIdx.x * blockDim.x + threadIdx.x;
    int stride = gridDim.x * blockDim.x;
    float s = 0.f;
    for (int i = idx; i < n4; i += stride) {
        float4 v = p[i];
        s += v.x * v.x + v.y * v.y + v.z * v.z + v.w * v.w;
    }
    float r = wave_reduce(s);
    __shared__ float part[4];
    int lane = threadIdx.x & 63, wv = threadIdx.x >> 6;
    if (lane == 0) part[wv] = r;
    __syncthreads();
    if (threadIdx.x == 0)
        atomicAdd(acc, (double)(part[0] + part[1] + part[2] + part[3]));
}

__global__ void k_final(const double* __restrict__ accs, float* __restrict__ out) {
    double loss = accs[0] / (double)BB + (0.01 / (2.0 * (double)BB)) * (accs[1] + accs[2]);
    out[0] = (float)loss;
}

extern "C" void kernel_launch(void* const* d_in, const int* in_sizes, int n_in,
                              void* d_out, int out_size, void* d_ws, size_t ws_size,
                              hipStream_t stream) {
    const float* rv   = (const float*)d_in[0];
    const float* rd   = (const float*)d_in[1];
    const float* proj = (const float*)d_in[2];
    const float* beta = (const float*)d_in[3];
    const int* wid    = (const int*)d_in[4];
    const int* doc    = (const int*)d_in[5];
    const int* neg    = (const int*)d_in[6];
    float* out = (float*)d_out;
    char* ws = (char*)d_ws;

    // Big-path layout: rdT (102.4 MB) at 0; rvT (60.8 MB padded) aliases it
    // (dead before rdT written).
    const size_t off_big    = 0;
    const size_t off_normed = 102400000;
    const size_t off_tpre   = off_normed + 4915200;
    const size_t off_small  = off_tpre + 4194304;
    const size_t need = off_small + 1024 + 1024 + 2048 + 2048 + 24;

    if (ws_size >= need) {
        float*  rvT    = (float*)(ws + off_big);
        float*  rdT    = (float*)(ws + off_big);
        float*  normed = (float*)(ws + off_normed);
        float*  tpre   = (float*)(ws + off_tpre);
        float*  meanf  = (float*)(ws + off_small);
        float*  scalef = (float*)(ws + off_small + 1024);
        double* rowsum = (double*)(ws + off_small + 2048);
        double* rowsq  = (double*)(ws + off_small + 4096);
        double* accs   = (double*)(ws + off_small + 6144);

        k_init<<<3, 256, 0, stream>>>(rowsum, 515);
        k_trv<<<1024, 256, 0, stream>>>(rv, rvT);
        k_gather2<<<BB / 4, 256, 0, stream>>>(rvT, wid, normed);
        k_gemm<<<dim3(64, 4), 256, 0, stream>>>(proj, normed, tpre);
        k_stats1<<<64, 256, 0, stream>>>(tpre, rowsum, rowsq);
        k_stats2<<<1, 256, 0, stream>>>(rowsum, rowsq, meanf, scalef);
        k_trd<<<1024, 256, 0, stream>>>(rd, rdT, accs + 1);
        k_loss2<<<BB / 4, 256, 0, stream>>>(tpre, meanf, scalef, beta, rdT, doc, neg, accs);
        k_reg<<<75, 256, 0, stream>>>((const float4*)proj, 19200, accs + 2);
        k_final<<<1, 1, 0, stream>>>(accs, out);
    } else {
        // Fallback: strided path (9.2 MB workspace)
        float*  normed = (float*)(ws);
        float*  tpre   = (float*)(ws + 4915200);
        float*  meanf  = (float*)(ws + 9109504);
        float*  scalef = (float*)(ws + 9110528);
        double* rowsum = (double*)(ws + 9111552);
        double* rowsq  = (double*)(ws + 9113600);
        double* accs   = (double*)(ws + 9115648);

        k_init<<<3, 256, 0, stream>>>(rowsum, 515);
        k_gather<<<BB, 320, 0, stream>>>(rv, wid, normed);
        k_gemm<<<dim3(64, 4), 256, 0, stream>>>(proj, normed, tpre);
        k_stats1<<<64, 256, 0, stream>>>(tpre, rowsum, rowsq);
        k_stats2<<<1, 256, 0, stream>>>(rowsum, rowsq, meanf, scalef);
        k_loss<<<BB, 256, 0, stream>>>(tpre, meanf, scalef, beta, rd, doc, neg, accs);
        k_reg<<<1024, 256, 0, stream>>>((const float4*)rd, 6400000, accs + 1);
        k_reg<<<75, 256, 0, stream>>>((const float4*)proj, 19200, accs + 2);
        k_final<<<1, 1, 0, stream>>>(accs, out);
    }
}